// Round 11
// baseline (291.870 us; speedup 1.0000x reference)
//
#include <hip/hip_runtime.h>
#include <math.h>

#define BB 4
#define NN 8192
#define MM 2048
#define CC 64
#define KNB 32
#define CIN 67   // 3 + CC
#define H1 64
#define H2 128
#define XP 36    // padded row stride for x^T / h1^T tile

// ---------------- init: zero per-batch maxnorm cells ----------------
__global__ void init_kernel(int* maxnorm) {
    if (threadIdx.x < BB) maxnorm[threadIdx.x] = 0;
}

// ---------------- c2 precompute (validated round 6) ----------------
__global__ __launch_bounds__(256) void c2_kernel(const float* __restrict__ coord,
                                                 float* __restrict__ c2buf) {
    const int t = blockIdx.x * 256 + threadIdx.x;   // t in [0, BB*NN)
    if (t < BB * NN) {
        float cx = coord[t * 3 + 0], cy = coord[t * 3 + 1], cz = coord[t * 3 + 2];
        c2buf[t] = __fadd_rn(__fadd_rn(__fmul_rn(cx, cx), __fmul_rn(cy, cy)), __fmul_rn(cz, cz));
    }
}

// ---------------- weight transpose: W1T[h][c] (c pad 68, col 67 = 0), W2T[h2][c] ----------------
__global__ __launch_bounds__(256) void wtrans_kernel(const float* __restrict__ W1,
                                                     const float* __restrict__ W2,
                                                     float* __restrict__ w1t,
                                                     float* __restrict__ w2t) {
    const int t = blockIdx.x * 256 + threadIdx.x;
    if (t < H1 * 68) {
        const int h = t / 68, c = t % 68;
        w1t[t] = (c < CIN) ? W1[c * H1 + h] : 0.0f;
    } else {
        const int u = t - H1 * 68;
        if (u < H2 * H1) {
            const int h = u / H1, c = u % H1;
            w2t[u] = W2[c * H2 + h];
        }
    }
}

// ---------------- kNN: register radix select + U-prefilter (validated round 9) ----------------
__global__ __launch_bounds__(256, 4) void knn_kernel(
    const float* __restrict__ coord, const float* __restrict__ anchor_coord,
    const float* __restrict__ c2buf,
    int* __restrict__ idxbuf, int* __restrict__ maxnorm)
{
    __shared__ unsigned hist[4][256];     // per-wave histogram copies
    __shared__ unsigned wmax[4];
    __shared__ unsigned wtot[4];
    __shared__ unsigned bc[2];            // [0]=chosen bin, [1]=rank within bin
    __shared__ unsigned nsel;
    __shared__ int      selcell;
    __shared__ int      sel_s[KNB];

    const int anchor = blockIdx.x;
    const int b  = anchor >> 11;          // / MM
    const int mi = anchor & (MM - 1);
    const int tid = threadIdx.x;
    const int w = tid >> 6, lane = tid & 63;

    const float ax = anchor_coord[(b * MM + mi) * 3 + 0];
    const float ay = anchor_coord[(b * MM + mi) * 3 + 1];
    const float az = anchor_coord[(b * MM + mi) * 3 + 2];
    const float a2 = __fadd_rn(__fadd_rn(__fmul_rn(ax, ax), __fmul_rn(ay, ay)), __fmul_rn(az, az));

    const float* cb  = coord + (size_t)b * NN * 3;
    const float* c2b = c2buf + (size_t)b * NN;

    unsigned kreg[32];
    unsigned tmin = 0xFFFFFFFFu;
    #pragma unroll
    for (int j = 0; j < 32; j++) {
        const int i = tid + 256 * j;
        float cx = cb[i * 3 + 0], cy = cb[i * 3 + 1], cz = cb[i * 3 + 2];
        float c2 = c2b[i];
        float dt = __fadd_rn(__fadd_rn(__fmul_rn(ax, cx), __fmul_rn(ay, cy)), __fmul_rn(az, cz));
        float d2 = __fadd_rn(__fsub_rn(a2, __fmul_rn(2.0f, dt)), c2);
        unsigned ub = __float_as_uint(d2);
        ub ^= (unsigned)((int)ub >> 31) | 0x80000000u;   // monotone: u32 order == float order
        kreg[j] = ub;
        tmin = tmin < ub ? tmin : ub;
    }

    unsigned um = tmin;
    um = max(um, (unsigned)__shfl_xor((int)um, 1));
    um = max(um, (unsigned)__shfl_xor((int)um, 2));
    um = max(um, (unsigned)__shfl_xor((int)um, 4));
    if (lane == 0) wmax[w] = um;
    if (tid == 0) nsel = 0;
    __syncthreads();
    const unsigned U = max(max(wmax[0], wmax[1]), max(wmax[2], wmax[3]));

    unsigned prefix = 0, pmask = 0;
    unsigned k = KNB;

    #pragma unroll
    for (int pass = 0; pass < 4; pass++) {
        const int sh = 24 - 8 * pass;
        unsigned* hf = &hist[0][0];
        hf[tid] = 0; hf[tid + 256] = 0; hf[tid + 512] = 0; hf[tid + 768] = 0;
        __syncthreads();
        #pragma unroll
        for (int j = 0; j < 32; j++) {
            unsigned kk = kreg[j];
            if (kk <= U && (kk & pmask) == prefix) atomicAdd(&hist[w][(kk >> sh) & 0xFFu], 1u);
        }
        __syncthreads();
        const unsigned h = hist[0][tid] + hist[1][tid] + hist[2][tid] + hist[3][tid];
        unsigned v = h;
        #pragma unroll
        for (int d = 1; d < 64; d <<= 1) {
            unsigned t = __shfl_up(v, d);
            if (lane >= d) v += t;
        }
        if (lane == 63) wtot[w] = v;
        __syncthreads();
        unsigned off = 0;
        #pragma unroll
        for (int ww = 0; ww < 3; ww++) if (ww < w) off += wtot[ww];
        v += off;
        const unsigned excl = v - h;
        if (excl < k && k <= v) { bc[0] = (unsigned)tid; bc[1] = k - excl; }
        __syncthreads();
        prefix |= bc[0] << sh;
        pmask  |= 0xFFu << sh;
        k = bc[1];
    }
    const unsigned T = prefix;

    unsigned tiemask = 0;
    #pragma unroll
    for (int j = 0; j < 32; j++) {
        unsigned kk = kreg[j];
        if (kk < T) { unsigned pos = atomicAdd(&nsel, 1u); sel_s[pos] = tid + 256 * j; }
        else if (kk == T) tiemask |= 1u << j;
    }
    __syncthreads();
    const unsigned n_lt = nsel;
    const unsigned needed = KNB - n_lt;
    int last = -1;
    for (unsigned r = 0; r < needed; r++) {
        if (tid == 0) selcell = 0x7fffffff;
        __syncthreads();
        unsigned m = tiemask;
        while (m) {
            int j = __ffs(m) - 1; m &= m - 1;
            int idx = tid + 256 * j;
            if (idx > last) atomicMin(&selcell, idx);
        }
        __syncthreads();
        last = selcell;
        if (tid == 0) sel_s[n_lt + r] = last;
        __syncthreads();
    }

    float nrm = 0.0f;
    if (tid < KNB) {
        int j = sel_s[tid];
        idxbuf[anchor * KNB + tid] = j;
        float dx = __fsub_rn(cb[j * 3 + 0], ax);
        float dy = __fsub_rn(cb[j * 3 + 1], ay);
        float dz = __fsub_rn(cb[j * 3 + 2], az);
        nrm = sqrtf(dx * dx + dy * dy + dz * dz);
    }
    if (tid < 64) {
        #pragma unroll
        for (int off = 32; off; off >>= 1) nrm = fmaxf(nrm, __shfl_xor(nrm, off));
        if (tid == 0) atomicMax(&maxnorm[b], __float_as_int(nrm));
    }
}

// ---------------- fused gather + MLP + maxpool: one block per anchor ----------------
// NEW: transposed-weight float4 loads (17+32 vector loads vs 195 scalar) — FMA
// order unchanged => bit-exact. h1 tile overlays x tile (extra barrier) => LDS ~12.5KB.
__global__ __launch_bounds__(256, 6) void mlp_kernel(
    const float* __restrict__ feat, const float* __restrict__ coord,
    const float* __restrict__ anchor_feat, const float* __restrict__ anchor_coord,
    const float* __restrict__ w1t, const float* __restrict__ b1,
    const float* __restrict__ g1, const float* __restrict__ be1,
    const float* __restrict__ w2t, const float* __restrict__ b2,
    const float* __restrict__ g2, const float* __restrict__ be2,
    const int* __restrict__ maxnorm, const int* __restrict__ idxbuf,
    float* __restrict__ out)
{
    __shared__ __align__(16) float xst[68 * XP];     // x^T [j][k] (rows 0..67); reused as h1^T [ch][k]
    __shared__ int   sel[KNB];
    __shared__ float pmax[4 * H2];

    const int anchor = blockIdx.x;
    const int b  = anchor >> 11;
    const int mi = anchor & (MM - 1);
    const int tid = threadIdx.x;
    const int w = tid >> 6, lane = tid & 63;

    if (tid < KNB) sel[tid] = idxbuf[anchor * KNB + tid];
    __syncthreads();

    const float mn = __int_as_float(maxnorm[b]);

    // ---- coalesced gather: wave w owns neighbors k = 8w..8w+7; lane = feature channel ----
    {
        const float af = anchor_feat[((size_t)b * MM + mi) * CC + lane];
        #pragma unroll
        for (int kk = 0; kk < 8; kk++) {
            const int k = w * 8 + kk;
            const int nj = sel[k];
            float fv = feat[((size_t)b * NN + nj) * CC + lane] - af;
            xst[(3 + lane) * XP + k] = fv;
        }
    }
    if (tid < 128) {
        const int k = tid >> 2, j = tid & 3;
        if (j < 3) {
            const int nj = sel[k];
            float d = __fsub_rn(coord[((size_t)b * NN + nj) * 3 + j],
                                anchor_coord[((size_t)b * MM + mi) * 3 + j]);
            xst[j * XP + k] = __fdiv_rn(d, mn);
        }
    }
    if (tid < KNB) xst[67 * XP + tid] = 0.0f;   // pad row (pairs with W1T zero col 67)
    __syncthreads();

    const int k0 = w * 8;   // this wave owns neighbors k0..k0+7; channel = lane

    // ---- stage 1: h1 = relu(LN(x @ W1 + b1)); W1T float4 loads ----
    const float* w1row = w1t + lane * 68;
    const float bias1 = b1[lane];
    float acc[8];
    #pragma unroll
    for (int kk = 0; kk < 8; kk++) acc[kk] = bias1;
    #pragma unroll 4
    for (int g = 0; g < 17; g++) {
        const float4 wq = *(const float4*)(w1row + g * 4);
        #pragma unroll
        for (int i = 0; i < 4; i++) {
            const int j = g * 4 + i;
            const float wv = (i == 0) ? wq.x : (i == 1) ? wq.y : (i == 2) ? wq.z : wq.w;
            const float4 xa = *(const float4*)&xst[j * XP + k0];
            const float4 xb = *(const float4*)&xst[j * XP + k0 + 4];
            acc[0] = fmaf(xa.x, wv, acc[0]);
            acc[1] = fmaf(xa.y, wv, acc[1]);
            acc[2] = fmaf(xa.z, wv, acc[2]);
            acc[3] = fmaf(xa.w, wv, acc[3]);
            acc[4] = fmaf(xb.x, wv, acc[4]);
            acc[5] = fmaf(xb.y, wv, acc[5]);
            acc[6] = fmaf(xb.z, wv, acc[6]);
            acc[7] = fmaf(xb.w, wv, acc[7]);
        }
    }
    const float g1v = g1[lane], be1v = be1[lane];
    float yreg[8];
    #pragma unroll
    for (int kk = 0; kk < 8; kk++) {
        float vv = acc[kk];
        float s = vv, s2 = vv * vv;
        #pragma unroll
        for (int off = 32; off; off >>= 1) { s += __shfl_xor(s, off); s2 += __shfl_xor(s2, off); }
        float mu  = s  * (1.0f / H1);
        float var = s2 * (1.0f / H1) - mu * mu;
        float r = rsqrtf(var + 1e-6f);
        float y = fmaf((vv - mu) * r, g1v, be1v);
        yreg[kk] = fmaxf(y, 0.0f);
    }
    __syncthreads();                       // all waves done READING x tile
    #pragma unroll
    for (int kk = 0; kk < 8; kk++) xst[lane * XP + k0 + kk] = yreg[kk];   // h1^T overlays x^T
    __syncthreads();

    // ---- stage 2: h2 = relu(LN(h1 @ W2 + b2)), maxpool over k; W2T float4 loads ----
    const float* w2rowA = w2t + (size_t)lane * 64;
    const float* w2rowB = w2t + (size_t)(lane + 64) * 64;
    const float bias2a = b2[lane], bias2b = b2[lane + 64];
    float a[16];
    #pragma unroll
    for (int kk = 0; kk < 8; kk++) { a[kk] = bias2a; a[8 + kk] = bias2b; }
    #pragma unroll 2
    for (int g = 0; g < 16; g++) {
        const float4 wq0 = *(const float4*)(w2rowA + g * 4);
        const float4 wq1 = *(const float4*)(w2rowB + g * 4);
        #pragma unroll
        for (int i = 0; i < 4; i++) {
            const int j = g * 4 + i;
            const float w0 = (i == 0) ? wq0.x : (i == 1) ? wq0.y : (i == 2) ? wq0.z : wq0.w;
            const float w1 = (i == 0) ? wq1.x : (i == 1) ? wq1.y : (i == 2) ? wq1.z : wq1.w;
            const float4 ha = *(const float4*)&xst[j * XP + k0];
            const float4 hb = *(const float4*)&xst[j * XP + k0 + 4];
            a[0] = fmaf(ha.x, w0, a[0]);   a[8]  = fmaf(ha.x, w1, a[8]);
            a[1] = fmaf(ha.y, w0, a[1]);   a[9]  = fmaf(ha.y, w1, a[9]);
            a[2] = fmaf(ha.z, w0, a[2]);   a[10] = fmaf(ha.z, w1, a[10]);
            a[3] = fmaf(ha.w, w0, a[3]);   a[11] = fmaf(ha.w, w1, a[11]);
            a[4] = fmaf(hb.x, w0, a[4]);   a[12] = fmaf(hb.x, w1, a[12]);
            a[5] = fmaf(hb.y, w0, a[5]);   a[13] = fmaf(hb.y, w1, a[13]);
            a[6] = fmaf(hb.z, w0, a[6]);   a[14] = fmaf(hb.z, w1, a[14]);
            a[7] = fmaf(hb.w, w0, a[7]);   a[15] = fmaf(hb.w, w1, a[15]);
        }
    }
    const float g2a = g2[lane], g2b = g2[lane + 64];
    const float be2a = be2[lane], be2b = be2[lane + 64];
    float mx0 = -INFINITY, mx1 = -INFINITY;
    #pragma unroll
    for (int kk = 0; kk < 8; kk++) {
        float a0 = a[kk], a1 = a[8 + kk];
        float s = a0 + a1, s2 = a0 * a0 + a1 * a1;
        #pragma unroll
        for (int off = 32; off; off >>= 1) { s += __shfl_xor(s, off); s2 += __shfl_xor(s2, off); }
        float mu  = s  * (1.0f / H2);
        float var = s2 * (1.0f / H2) - mu * mu;
        float r = rsqrtf(var + 1e-6f);
        float y0 = fmaxf(fmaf((a0 - mu) * r, g2a, be2a), 0.0f);
        float y1 = fmaxf(fmaf((a1 - mu) * r, g2b, be2b), 0.0f);
        mx0 = fmaxf(mx0, y0);
        mx1 = fmaxf(mx1, y1);
    }
    pmax[w * H2 + lane]      = mx0;
    pmax[w * H2 + lane + 64] = mx1;
    __syncthreads();
    if (tid < H2) {
        float vv = pmax[tid];
        #pragma unroll
        for (int ww = 1; ww < 4; ww++) vv = fmaxf(vv, pmax[ww * H2 + tid]);
        out[(size_t)anchor * H2 + tid] = vv;
    }
}

extern "C" void kernel_launch(void* const* d_in, const int* in_sizes, int n_in,
                              void* d_out, int out_size, void* d_ws, size_t ws_size,
                              hipStream_t stream) {
    const float* feat         = (const float*)d_in[0];
    const float* coord        = (const float*)d_in[1];
    const float* anchor_feat  = (const float*)d_in[2];
    const float* anchor_coord = (const float*)d_in[3];
    const float* W1  = (const float*)d_in[4];
    const float* b1  = (const float*)d_in[5];
    const float* g1  = (const float*)d_in[6];
    const float* be1 = (const float*)d_in[7];
    const float* W2  = (const float*)d_in[8];
    const float* b2  = (const float*)d_in[9];
    const float* g2  = (const float*)d_in[10];
    const float* be2 = (const float*)d_in[11];
    float* out = (float*)d_out;

    int*   maxn   = (int*)d_ws;                                  // 16 ints
    int*   idxbuf = (int*)d_ws + 16;                             // BB*MM*KNB ints
    float* c2buf  = (float*)((int*)d_ws + 16 + BB * MM * KNB);   // BB*NN floats
    float* w1t    = c2buf + BB * NN;                             // 64*68 floats
    float* w2t    = w1t + H1 * 68;                               // 128*64 floats

    init_kernel<<<1, 64, 0, stream>>>(maxn);
    c2_kernel<<<(BB * NN + 255) / 256, 256, 0, stream>>>(coord, c2buf);
    wtrans_kernel<<<(H1 * 68 + H2 * H1 + 255) / 256, 256, 0, stream>>>(W1, W2, w1t, w2t);
    knn_kernel<<<BB * MM, 256, 0, stream>>>(coord, anchor_coord, c2buf, idxbuf, maxn);
    mlp_kernel<<<BB * MM, 256, 0, stream>>>(feat, coord, anchor_feat, anchor_coord,
                                            w1t, b1, g1, be1, w2t, b2, g2, be2,
                                            maxn, idxbuf, out);
}

// Round 12
// 267.015 us; speedup vs baseline: 1.0931x; 1.0931x over previous
//
#include <hip/hip_runtime.h>
#include <math.h>

#define BB 4
#define NN 8192
#define MM 2048
#define CC 64
#define KNB 32
#define CIN 67   // 3 + CC
#define H1 64
#define H2 128
#define XP 36    // padded row stride for x^T / h1^T tile

// ---------------- init: zero per-batch maxnorm cells ----------------
__global__ void init_kernel(int* maxnorm) {
    if (threadIdx.x < BB) maxnorm[threadIdx.x] = 0;
}

// ---------------- c2 precompute (validated round 6) ----------------
__global__ __launch_bounds__(256) void c2_kernel(const float* __restrict__ coord,
                                                 float* __restrict__ c2buf) {
    const int t = blockIdx.x * 256 + threadIdx.x;   // t in [0, BB*NN)
    if (t < BB * NN) {
        float cx = coord[t * 3 + 0], cy = coord[t * 3 + 1], cz = coord[t * 3 + 2];
        c2buf[t] = __fadd_rn(__fadd_rn(__fmul_rn(cx, cx), __fmul_rn(cy, cy)), __fmul_rn(cz, cz));
    }
}

// ---------------- kNN: register radix select + U-prefilter (validated round 9) ----------------
__global__ __launch_bounds__(256, 4) void knn_kernel(
    const float* __restrict__ coord, const float* __restrict__ anchor_coord,
    const float* __restrict__ c2buf,
    int* __restrict__ idxbuf, int* __restrict__ maxnorm)
{
    __shared__ unsigned hist[4][256];     // per-wave histogram copies
    __shared__ unsigned wmax[4];
    __shared__ unsigned wtot[4];
    __shared__ unsigned bc[2];            // [0]=chosen bin, [1]=rank within bin
    __shared__ unsigned nsel;
    __shared__ int      selcell;
    __shared__ int      sel_s[KNB];

    const int anchor = blockIdx.x;
    const int b  = anchor >> 11;          // / MM
    const int mi = anchor & (MM - 1);
    const int tid = threadIdx.x;
    const int w = tid >> 6, lane = tid & 63;

    const float ax = anchor_coord[(b * MM + mi) * 3 + 0];
    const float ay = anchor_coord[(b * MM + mi) * 3 + 1];
    const float az = anchor_coord[(b * MM + mi) * 3 + 2];
    const float a2 = __fadd_rn(__fadd_rn(__fmul_rn(ax, ax), __fmul_rn(ay, ay)), __fmul_rn(az, az));

    const float* cb  = coord + (size_t)b * NN * 3;
    const float* c2b = c2buf + (size_t)b * NN;

    unsigned kreg[32];
    unsigned tmin = 0xFFFFFFFFu;
    #pragma unroll
    for (int j = 0; j < 32; j++) {
        const int i = tid + 256 * j;
        float cx = cb[i * 3 + 0], cy = cb[i * 3 + 1], cz = cb[i * 3 + 2];
        float c2 = c2b[i];
        float dt = __fadd_rn(__fadd_rn(__fmul_rn(ax, cx), __fmul_rn(ay, cy)), __fmul_rn(az, cz));
        float d2 = __fadd_rn(__fsub_rn(a2, __fmul_rn(2.0f, dt)), c2);
        unsigned ub = __float_as_uint(d2);
        ub ^= (unsigned)((int)ub >> 31) | 0x80000000u;   // monotone: u32 order == float order
        kreg[j] = ub;
        tmin = tmin < ub ? tmin : ub;
    }

    unsigned um = tmin;
    um = max(um, (unsigned)__shfl_xor((int)um, 1));
    um = max(um, (unsigned)__shfl_xor((int)um, 2));
    um = max(um, (unsigned)__shfl_xor((int)um, 4));
    if (lane == 0) wmax[w] = um;
    if (tid == 0) nsel = 0;
    __syncthreads();
    const unsigned U = max(max(wmax[0], wmax[1]), max(wmax[2], wmax[3]));

    unsigned prefix = 0, pmask = 0;
    unsigned k = KNB;

    #pragma unroll
    for (int pass = 0; pass < 4; pass++) {
        const int sh = 24 - 8 * pass;
        unsigned* hf = &hist[0][0];
        hf[tid] = 0; hf[tid + 256] = 0; hf[tid + 512] = 0; hf[tid + 768] = 0;
        __syncthreads();
        #pragma unroll
        for (int j = 0; j < 32; j++) {
            unsigned kk = kreg[j];
            if (kk <= U && (kk & pmask) == prefix) atomicAdd(&hist[w][(kk >> sh) & 0xFFu], 1u);
        }
        __syncthreads();
        const unsigned h = hist[0][tid] + hist[1][tid] + hist[2][tid] + hist[3][tid];
        unsigned v = h;
        #pragma unroll
        for (int d = 1; d < 64; d <<= 1) {
            unsigned t = __shfl_up(v, d);
            if (lane >= d) v += t;
        }
        if (lane == 63) wtot[w] = v;
        __syncthreads();
        unsigned off = 0;
        #pragma unroll
        for (int ww = 0; ww < 3; ww++) if (ww < w) off += wtot[ww];
        v += off;
        const unsigned excl = v - h;
        if (excl < k && k <= v) { bc[0] = (unsigned)tid; bc[1] = k - excl; }
        __syncthreads();
        prefix |= bc[0] << sh;
        pmask  |= 0xFFu << sh;
        k = bc[1];
    }
    const unsigned T = prefix;

    unsigned tiemask = 0;
    #pragma unroll
    for (int j = 0; j < 32; j++) {
        unsigned kk = kreg[j];
        if (kk < T) { unsigned pos = atomicAdd(&nsel, 1u); sel_s[pos] = tid + 256 * j; }
        else if (kk == T) tiemask |= 1u << j;
    }
    __syncthreads();
    const unsigned n_lt = nsel;
    const unsigned needed = KNB - n_lt;
    int last = -1;
    for (unsigned r = 0; r < needed; r++) {
        if (tid == 0) selcell = 0x7fffffff;
        __syncthreads();
        unsigned m = tiemask;
        while (m) {
            int j = __ffs(m) - 1; m &= m - 1;
            int idx = tid + 256 * j;
            if (idx > last) atomicMin(&selcell, idx);
        }
        __syncthreads();
        last = selcell;
        if (tid == 0) sel_s[n_lt + r] = last;
        __syncthreads();
    }

    float nrm = 0.0f;
    if (tid < KNB) {
        int j = sel_s[tid];
        idxbuf[anchor * KNB + tid] = j;
        float dx = __fsub_rn(cb[j * 3 + 0], ax);
        float dy = __fsub_rn(cb[j * 3 + 1], ay);
        float dz = __fsub_rn(cb[j * 3 + 2], az);
        nrm = sqrtf(dx * dx + dy * dy + dz * dz);
    }
    if (tid < 64) {
        #pragma unroll
        for (int off = 32; off; off >>= 1) nrm = fmaxf(nrm, __shfl_xor(nrm, off));
        if (tid == 0) atomicMax(&maxnorm[b], __float_as_int(nrm));
    }
}

// ---------------- fused gather + MLP + maxpool: one block per anchor ----------------
// Register-blocked to cut DS-pipe instructions (the round-10 bottleneck):
// stage1 thread = 4 neighbors x 2 channels (1 x-float4 + 1 W1-float2 + 8 FMA per j);
// stage2 thread = 4 neighbors x 4 channels (1 h-float4 + 1 W2-float4 + 16 FMA per j).
// W loads use the ORIGINAL row-major layout (coalesced across lanes). Per-output
// j-accumulation order unchanged (bias-init, j ascending) => bit-exact outputs;
// LN reduction tree is 32-lane group (f32 reassociation noise only).
__global__ __launch_bounds__(256, 8) void mlp_kernel(
    const float* __restrict__ feat, const float* __restrict__ coord,
    const float* __restrict__ anchor_feat, const float* __restrict__ anchor_coord,
    const float* __restrict__ W1, const float* __restrict__ b1,
    const float* __restrict__ g1, const float* __restrict__ be1,
    const float* __restrict__ W2, const float* __restrict__ b2,
    const float* __restrict__ g2, const float* __restrict__ be2,
    const int* __restrict__ maxnorm, const int* __restrict__ idxbuf,
    float* __restrict__ out)
{
    __shared__ __align__(16) float xst[CIN * XP];    // x^T [j][k]; rows 0..63 reused as h1^T [ch][k]
    __shared__ int   sel[KNB];
    __shared__ __align__(16) float pmax[8][H2];

    const int anchor = blockIdx.x;
    const int b  = anchor >> 11;
    const int mi = anchor & (MM - 1);
    const int tid = threadIdx.x;
    const int w = tid >> 6, lane = tid & 63;

    if (tid < KNB) sel[tid] = idxbuf[anchor * KNB + tid];
    __syncthreads();

    const float mn = __int_as_float(maxnorm[b]);

    // ---- coalesced gather (validated round 10): wave w owns neighbors 8w..8w+7; lane = channel ----
    {
        const float af = anchor_feat[((size_t)b * MM + mi) * CC + lane];
        #pragma unroll
        for (int kk = 0; kk < 8; kk++) {
            const int k = w * 8 + kk;
            const int nj = sel[k];
            xst[(3 + lane) * XP + k] = feat[((size_t)b * NN + nj) * CC + lane] - af;
        }
    }
    if (tid < 128) {
        const int k = tid >> 2, j = tid & 3;
        if (j < 3) {
            const int nj = sel[k];
            float d = __fsub_rn(coord[((size_t)b * NN + nj) * 3 + j],
                                anchor_coord[((size_t)b * MM + mi) * 3 + j]);
            xst[j * XP + k] = __fdiv_rn(d, mn);
        }
    }
    __syncthreads();

    // ---- stage 1: thread = (kq1 = tid>>5 -> k = 4*kq1..+3) x (c1 = tid&31 -> ch = 2c1, 2c1+1) ----
    const int c1 = tid & 31, kq1 = tid >> 5;
    const int ch1 = 2 * c1;
    const float b1a = b1[ch1], b1b = b1[ch1 + 1];
    float accA[4], accB[4];
    #pragma unroll
    for (int kk = 0; kk < 4; kk++) { accA[kk] = b1a; accB[kk] = b1b; }
    #pragma unroll 4
    for (int j = 0; j < CIN; j++) {
        const float4 xq = *(const float4*)&xst[j * XP + 4 * kq1];
        const float2 wv = *(const float2*)&W1[j * H1 + ch1];
        accA[0] = fmaf(xq.x, wv.x, accA[0]);  accB[0] = fmaf(xq.x, wv.y, accB[0]);
        accA[1] = fmaf(xq.y, wv.x, accA[1]);  accB[1] = fmaf(xq.y, wv.y, accB[1]);
        accA[2] = fmaf(xq.z, wv.x, accA[2]);  accB[2] = fmaf(xq.z, wv.y, accB[2]);
        accA[3] = fmaf(xq.w, wv.x, accA[3]);  accB[3] = fmaf(xq.w, wv.y, accB[3]);
    }
    const float g1a = g1[ch1], g1b = g1[ch1 + 1];
    const float be1a = be1[ch1], be1b = be1[ch1 + 1];
    float y1A[4], y1B[4];
    #pragma unroll
    for (int kk = 0; kk < 4; kk++) {
        // LN over 64 channels of neighbor k = 4*kq1+kk: reduce over the 32-lane group (2 ch/thread)
        float s  = accA[kk] + accB[kk];
        float s2 = accA[kk] * accA[kk] + accB[kk] * accB[kk];
        #pragma unroll
        for (int off = 16; off; off >>= 1) { s += __shfl_xor(s, off); s2 += __shfl_xor(s2, off); }
        float mu  = s  * (1.0f / H1);
        float var = s2 * (1.0f / H1) - mu * mu;
        float r = rsqrtf(var + 1e-6f);
        y1A[kk] = fmaxf(fmaf((accA[kk] - mu) * r, g1a, be1a), 0.0f);
        y1B[kk] = fmaxf(fmaf((accB[kk] - mu) * r, g1b, be1b), 0.0f);
    }
    __syncthreads();                 // all x reads complete before overlay
    #pragma unroll
    for (int kk = 0; kk < 4; kk++) {
        xst[ch1 * XP + 4 * kq1 + kk]       = y1A[kk];   // h1^T[ch][k] overlays x^T
        xst[(ch1 + 1) * XP + 4 * kq1 + kk] = y1B[kk];
    }
    __syncthreads();

    // ---- stage 2: thread = (kq2 = tid>>5 -> k = 4*kq2..+3) x (c2 = tid&31 -> ch = 4c2..4c2+3) ----
    const int c2 = tid & 31, kq2 = tid >> 5;
    const int ch2 = 4 * c2;
    const float4 b2v = *(const float4*)&b2[ch2];
    float a0[4], a1[4], a2[4], a3[4];   // a{i}[kk] = acc for channel ch2+i, neighbor 4*kq2+kk
    #pragma unroll
    for (int kk = 0; kk < 4; kk++) { a0[kk] = b2v.x; a1[kk] = b2v.y; a2[kk] = b2v.z; a3[kk] = b2v.w; }
    #pragma unroll 4
    for (int j = 0; j < H1; j++) {
        const float4 hq = *(const float4*)&xst[j * XP + 4 * kq2];
        const float4 wv = *(const float4*)&W2[j * H2 + ch2];
        a0[0] = fmaf(hq.x, wv.x, a0[0]); a1[0] = fmaf(hq.x, wv.y, a1[0]); a2[0] = fmaf(hq.x, wv.z, a2[0]); a3[0] = fmaf(hq.x, wv.w, a3[0]);
        a0[1] = fmaf(hq.y, wv.x, a0[1]); a1[1] = fmaf(hq.y, wv.y, a1[1]); a2[1] = fmaf(hq.y, wv.z, a2[1]); a3[1] = fmaf(hq.y, wv.w, a3[1]);
        a0[2] = fmaf(hq.z, wv.x, a0[2]); a1[2] = fmaf(hq.z, wv.y, a1[2]); a2[2] = fmaf(hq.z, wv.z, a2[2]); a3[2] = fmaf(hq.z, wv.w, a3[2]);
        a0[3] = fmaf(hq.w, wv.x, a0[3]); a1[3] = fmaf(hq.w, wv.y, a1[3]); a2[3] = fmaf(hq.w, wv.z, a2[3]); a3[3] = fmaf(hq.w, wv.w, a3[3]);
    }
    const float4 g2v  = *(const float4*)&g2[ch2];
    const float4 be2v = *(const float4*)&be2[ch2];
    float mx0 = -INFINITY, mx1 = -INFINITY, mx2 = -INFINITY, mx3 = -INFINITY;
    #pragma unroll
    for (int kk = 0; kk < 4; kk++) {
        // LN over 128 channels of neighbor k = 4*kq2+kk: reduce over the 32-lane group (4 ch/thread)
        float s  = (a0[kk] + a1[kk]) + (a2[kk] + a3[kk]);
        float s2 = (a0[kk] * a0[kk] + a1[kk] * a1[kk]) + (a2[kk] * a2[kk] + a3[kk] * a3[kk]);
        #pragma unroll
        for (int off = 16; off; off >>= 1) { s += __shfl_xor(s, off); s2 += __shfl_xor(s2, off); }
        float mu  = s  * (1.0f / H2);
        float var = s2 * (1.0f / H2) - mu * mu;
        float r = rsqrtf(var + 1e-6f);
        mx0 = fmaxf(mx0, fmaxf(fmaf((a0[kk] - mu) * r, g2v.x, be2v.x), 0.0f));
        mx1 = fmaxf(mx1, fmaxf(fmaf((a1[kk] - mu) * r, g2v.y, be2v.y), 0.0f));
        mx2 = fmaxf(mx2, fmaxf(fmaf((a2[kk] - mu) * r, g2v.z, be2v.z), 0.0f));
        mx3 = fmaxf(mx3, fmaxf(fmaf((a3[kk] - mu) * r, g2v.w, be2v.w), 0.0f));
    }
    float4 mxq; mxq.x = mx0; mxq.y = mx1; mxq.z = mx2; mxq.w = mx3;
    *(float4*)&pmax[kq2][ch2] = mxq;
    __syncthreads();
    if (tid < H2) {
        float vv = pmax[0][tid];
        #pragma unroll
        for (int r = 1; r < 8; r++) vv = fmaxf(vv, pmax[r][tid]);
        out[(size_t)anchor * H2 + tid] = vv;
    }
}

extern "C" void kernel_launch(void* const* d_in, const int* in_sizes, int n_in,
                              void* d_out, int out_size, void* d_ws, size_t ws_size,
                              hipStream_t stream) {
    const float* feat         = (const float*)d_in[0];
    const float* coord        = (const float*)d_in[1];
    const float* anchor_feat  = (const float*)d_in[2];
    const float* anchor_coord = (const float*)d_in[3];
    const float* W1  = (const float*)d_in[4];
    const float* b1  = (const float*)d_in[5];
    const float* g1  = (const float*)d_in[6];
    const float* be1 = (const float*)d_in[7];
    const float* W2  = (const float*)d_in[8];
    const float* b2  = (const float*)d_in[9];
    const float* g2  = (const float*)d_in[10];
    const float* be2 = (const float*)d_in[11];
    float* out = (float*)d_out;

    int*   maxn   = (int*)d_ws;                                  // 16 ints
    int*   idxbuf = (int*)d_ws + 16;                             // BB*MM*KNB ints
    float* c2buf  = (float*)((int*)d_ws + 16 + BB * MM * KNB);   // BB*NN floats

    init_kernel<<<1, 64, 0, stream>>>(maxn);
    c2_kernel<<<(BB * NN + 255) / 256, 256, 0, stream>>>(coord, c2buf);
    knn_kernel<<<BB * MM, 256, 0, stream>>>(coord, anchor_coord, c2buf, idxbuf, maxn);
    mlp_kernel<<<BB * MM, 256, 0, stream>>>(feat, coord, anchor_feat, anchor_coord,
                                            W1, b1, g1, be1, W2, b2, g2, be2,
                                            maxn, idxbuf, out);
}

// Round 13
// 226.369 us; speedup vs baseline: 1.2894x; 1.1796x over previous
//
#include <hip/hip_runtime.h>
#include <math.h>

#define BB 4
#define NN 8192
#define MM 2048
#define CC 64
#define KNB 32
#define CIN 67   // 3 + CC
#define H1 64
#define H2 128
#define XP 36    // padded row stride for x^T / h1^T tile (float4-aligned)
#define AB 4     // anchors per mlp block

// ---------------- init: zero per-batch maxnorm cells ----------------
__global__ void init_kernel(int* maxnorm) {
    if (threadIdx.x < BB) maxnorm[threadIdx.x] = 0;
}

// ---------------- c2 precompute (validated round 6) ----------------
__global__ __launch_bounds__(256) void c2_kernel(const float* __restrict__ coord,
                                                 float* __restrict__ c2buf) {
    const int t = blockIdx.x * 256 + threadIdx.x;   // t in [0, BB*NN)
    if (t < BB * NN) {
        float cx = coord[t * 3 + 0], cy = coord[t * 3 + 1], cz = coord[t * 3 + 2];
        c2buf[t] = __fadd_rn(__fadd_rn(__fmul_rn(cx, cx), __fmul_rn(cy, cy)), __fmul_rn(cz, cz));
    }
}

// ---------------- kNN: register radix select + U-prefilter (validated round 9) ----------------
__global__ __launch_bounds__(256, 4) void knn_kernel(
    const float* __restrict__ coord, const float* __restrict__ anchor_coord,
    const float* __restrict__ c2buf,
    int* __restrict__ idxbuf, int* __restrict__ maxnorm)
{
    __shared__ unsigned hist[4][256];     // per-wave histogram copies
    __shared__ unsigned wmax[4];
    __shared__ unsigned wtot[4];
    __shared__ unsigned bc[2];            // [0]=chosen bin, [1]=rank within bin
    __shared__ unsigned nsel;
    __shared__ int      selcell;
    __shared__ int      sel_s[KNB];

    const int anchor = blockIdx.x;
    const int b  = anchor >> 11;          // / MM
    const int mi = anchor & (MM - 1);
    const int tid = threadIdx.x;
    const int w = tid >> 6, lane = tid & 63;

    const float ax = anchor_coord[(b * MM + mi) * 3 + 0];
    const float ay = anchor_coord[(b * MM + mi) * 3 + 1];
    const float az = anchor_coord[(b * MM + mi) * 3 + 2];
    const float a2 = __fadd_rn(__fadd_rn(__fmul_rn(ax, ax), __fmul_rn(ay, ay)), __fmul_rn(az, az));

    const float* cb  = coord + (size_t)b * NN * 3;
    const float* c2b = c2buf + (size_t)b * NN;

    unsigned kreg[32];
    unsigned tmin = 0xFFFFFFFFu;
    #pragma unroll
    for (int j = 0; j < 32; j++) {
        const int i = tid + 256 * j;
        float cx = cb[i * 3 + 0], cy = cb[i * 3 + 1], cz = cb[i * 3 + 2];
        float c2 = c2b[i];
        float dt = __fadd_rn(__fadd_rn(__fmul_rn(ax, cx), __fmul_rn(ay, cy)), __fmul_rn(az, cz));
        float d2 = __fadd_rn(__fsub_rn(a2, __fmul_rn(2.0f, dt)), c2);
        unsigned ub = __float_as_uint(d2);
        ub ^= (unsigned)((int)ub >> 31) | 0x80000000u;   // monotone: u32 order == float order
        kreg[j] = ub;
        tmin = tmin < ub ? tmin : ub;
    }

    unsigned um = tmin;
    um = max(um, (unsigned)__shfl_xor((int)um, 1));
    um = max(um, (unsigned)__shfl_xor((int)um, 2));
    um = max(um, (unsigned)__shfl_xor((int)um, 4));
    if (lane == 0) wmax[w] = um;
    if (tid == 0) nsel = 0;
    __syncthreads();
    const unsigned U = max(max(wmax[0], wmax[1]), max(wmax[2], wmax[3]));

    unsigned prefix = 0, pmask = 0;
    unsigned k = KNB;

    #pragma unroll
    for (int pass = 0; pass < 4; pass++) {
        const int sh = 24 - 8 * pass;
        unsigned* hf = &hist[0][0];
        hf[tid] = 0; hf[tid + 256] = 0; hf[tid + 512] = 0; hf[tid + 768] = 0;
        __syncthreads();
        #pragma unroll
        for (int j = 0; j < 32; j++) {
            unsigned kk = kreg[j];
            if (kk <= U && (kk & pmask) == prefix) atomicAdd(&hist[w][(kk >> sh) & 0xFFu], 1u);
        }
        __syncthreads();
        const unsigned h = hist[0][tid] + hist[1][tid] + hist[2][tid] + hist[3][tid];
        unsigned v = h;
        #pragma unroll
        for (int d = 1; d < 64; d <<= 1) {
            unsigned t = __shfl_up(v, d);
            if (lane >= d) v += t;
        }
        if (lane == 63) wtot[w] = v;
        __syncthreads();
        unsigned off = 0;
        #pragma unroll
        for (int ww = 0; ww < 3; ww++) if (ww < w) off += wtot[ww];
        v += off;
        const unsigned excl = v - h;
        if (excl < k && k <= v) { bc[0] = (unsigned)tid; bc[1] = k - excl; }
        __syncthreads();
        prefix |= bc[0] << sh;
        pmask  |= 0xFFu << sh;
        k = bc[1];
    }
    const unsigned T = prefix;

    unsigned tiemask = 0;
    #pragma unroll
    for (int j = 0; j < 32; j++) {
        unsigned kk = kreg[j];
        if (kk < T) { unsigned pos = atomicAdd(&nsel, 1u); sel_s[pos] = tid + 256 * j; }
        else if (kk == T) tiemask |= 1u << j;
    }
    __syncthreads();
    const unsigned n_lt = nsel;
    const unsigned needed = KNB - n_lt;
    int last = -1;
    for (unsigned r = 0; r < needed; r++) {
        if (tid == 0) selcell = 0x7fffffff;
        __syncthreads();
        unsigned m = tiemask;
        while (m) {
            int j = __ffs(m) - 1; m &= m - 1;
            int idx = tid + 256 * j;
            if (idx > last) atomicMin(&selcell, idx);
        }
        __syncthreads();
        last = selcell;
        if (tid == 0) sel_s[n_lt + r] = last;
        __syncthreads();
    }

    float nrm = 0.0f;
    if (tid < KNB) {
        int j = sel_s[tid];
        idxbuf[anchor * KNB + tid] = j;
        float dx = __fsub_rn(cb[j * 3 + 0], ax);
        float dy = __fsub_rn(cb[j * 3 + 1], ay);
        float dz = __fsub_rn(cb[j * 3 + 2], az);
        nrm = sqrtf(dx * dx + dy * dy + dz * dz);
    }
    if (tid < 64) {
        #pragma unroll
        for (int off = 32; off; off >>= 1) nrm = fmaxf(nrm, __shfl_xor(nrm, off));
        if (tid == 0) atomicMax(&maxnorm[b], __float_as_int(nrm));
    }
}

// ---------------- fused gather + MLP + maxpool: FOUR anchors per block ----------------
// W loads hoisted: per j, one W1-float2 / W2-float4 register load is reused across
// 4 anchors (4x less W cache traffic per anchor — the round-12 bottleneck).
// Per-output FMA order (bias-init, ascending j) identical to validated r12 kernel.
// Group g = tid>>5 handles k-quad g (k=4g..4g+3) of each anchor; c = tid&31.
__global__ __launch_bounds__(256, 4) void mlp_kernel(
    const float* __restrict__ feat, const float* __restrict__ coord,
    const float* __restrict__ anchor_feat, const float* __restrict__ anchor_coord,
    const float* __restrict__ W1, const float* __restrict__ b1,
    const float* __restrict__ g1, const float* __restrict__ be1,
    const float* __restrict__ W2, const float* __restrict__ b2,
    const float* __restrict__ g2, const float* __restrict__ be2,
    const int* __restrict__ maxnorm, const int* __restrict__ idxbuf,
    float* __restrict__ out)
{
    __shared__ __align__(16) float xst[AB][CIN * XP];  // x^T per anchor; rows 0..63 reused as h1^T
    __shared__ int sel[AB][KNB];

    const int a0g = blockIdx.x * AB;      // first anchor of this block
    const int b   = a0g >> 11;            // all AB anchors share the batch
    const int tid = threadIdx.x;
    const int w = tid >> 6, lane = tid & 63;
    const int g = tid >> 5, c = tid & 31; // group (k-quad) and channel-thread

    if (tid < AB * KNB) sel[tid >> 5][tid & 31] = idxbuf[(size_t)a0g * KNB + tid];
    __syncthreads();

    const float mn = __int_as_float(maxnorm[b]);

    // ---- gather: wave w owns anchor w (coalesced: lane = feature channel) ----
    {
        const int mi = (a0g + w) & (MM - 1);
        const float af = anchor_feat[((size_t)b * MM + mi) * CC + lane];
        #pragma unroll 8
        for (int kk = 0; kk < KNB; kk++) {
            const int nj = sel[w][kk];
            xst[w][(3 + lane) * XP + kk] = feat[((size_t)b * NN + nj) * CC + lane] - af;
        }
    }
    for (int t = tid; t < AB * KNB * 3; t += 256) {
        const int a = t / 96, r = t % 96, k = r / 3, j = r % 3;
        const int mi = (a0g + a) & (MM - 1);
        const int nj = sel[a][k];
        float d = __fsub_rn(coord[((size_t)b * NN + nj) * 3 + j],
                            anchor_coord[((size_t)b * MM + mi) * 3 + j]);
        xst[a][j * XP + k] = __fdiv_rn(d, mn);
    }
    __syncthreads();

    // ---- stage 1: ch = 2c, 2c+1; k = 4g..4g+3 of each anchor ----
    const int ch1 = 2 * c;
    const float b1a = b1[ch1], b1b = b1[ch1 + 1];
    float accA[AB][4], accB[AB][4];
    #pragma unroll
    for (int a = 0; a < AB; a++)
        #pragma unroll
        for (int kk = 0; kk < 4; kk++) { accA[a][kk] = b1a; accB[a][kk] = b1b; }
    #pragma unroll 4
    for (int j = 0; j < CIN; j++) {
        const float2 wv = *(const float2*)&W1[j * H1 + ch1];
        #pragma unroll
        for (int a = 0; a < AB; a++) {
            const float4 xq = *(const float4*)&xst[a][j * XP + 4 * g];
            accA[a][0] = fmaf(xq.x, wv.x, accA[a][0]);  accB[a][0] = fmaf(xq.x, wv.y, accB[a][0]);
            accA[a][1] = fmaf(xq.y, wv.x, accA[a][1]);  accB[a][1] = fmaf(xq.y, wv.y, accB[a][1]);
            accA[a][2] = fmaf(xq.z, wv.x, accA[a][2]);  accB[a][2] = fmaf(xq.z, wv.y, accB[a][2]);
            accA[a][3] = fmaf(xq.w, wv.x, accA[a][3]);  accB[a][3] = fmaf(xq.w, wv.y, accB[a][3]);
        }
    }
    const float g1a = g1[ch1], g1b = g1[ch1 + 1];
    const float be1a = be1[ch1], be1b = be1[ch1 + 1];
    float y1A[AB][4], y1B[AB][4];
    #pragma unroll
    for (int a = 0; a < AB; a++) {
        #pragma unroll
        for (int kk = 0; kk < 4; kk++) {
            float s  = accA[a][kk] + accB[a][kk];
            float s2 = accA[a][kk] * accA[a][kk] + accB[a][kk] * accB[a][kk];
            #pragma unroll
            for (int off = 16; off; off >>= 1) { s += __shfl_xor(s, off); s2 += __shfl_xor(s2, off); }
            float mu  = s  * (1.0f / H1);
            float var = s2 * (1.0f / H1) - mu * mu;
            float r = rsqrtf(var + 1e-6f);
            y1A[a][kk] = fmaxf(fmaf((accA[a][kk] - mu) * r, g1a, be1a), 0.0f);
            y1B[a][kk] = fmaxf(fmaf((accB[a][kk] - mu) * r, g1b, be1b), 0.0f);
        }
    }
    __syncthreads();                 // all x reads complete before overlay
    #pragma unroll
    for (int a = 0; a < AB; a++)
        #pragma unroll
        for (int kk = 0; kk < 4; kk++) {
            xst[a][ch1 * XP + 4 * g + kk]       = y1A[a][kk];
            xst[a][(ch1 + 1) * XP + 4 * g + kk] = y1B[a][kk];
        }
    __syncthreads();

    // ---- stage 2: ch = 4c..4c+3; k = 4g..4g+3 of each anchor ----
    const int ch2 = 4 * c;
    const float4 b2v = *(const float4*)&b2[ch2];
    float a2c[AB][16];   // [anchor][ci*4+kk]
    #pragma unroll
    for (int a = 0; a < AB; a++)
        #pragma unroll
        for (int kk = 0; kk < 4; kk++) {
            a2c[a][0 * 4 + kk] = b2v.x; a2c[a][1 * 4 + kk] = b2v.y;
            a2c[a][2 * 4 + kk] = b2v.z; a2c[a][3 * 4 + kk] = b2v.w;
        }
    #pragma unroll 2
    for (int j = 0; j < H1; j++) {
        const float4 wv = *(const float4*)&W2[j * H2 + ch2];
        #pragma unroll
        for (int a = 0; a < AB; a++) {
            const float4 hq = *(const float4*)&xst[a][j * XP + 4 * g];
            a2c[a][0]  = fmaf(hq.x, wv.x, a2c[a][0]);  a2c[a][1]  = fmaf(hq.y, wv.x, a2c[a][1]);
            a2c[a][2]  = fmaf(hq.z, wv.x, a2c[a][2]);  a2c[a][3]  = fmaf(hq.w, wv.x, a2c[a][3]);
            a2c[a][4]  = fmaf(hq.x, wv.y, a2c[a][4]);  a2c[a][5]  = fmaf(hq.y, wv.y, a2c[a][5]);
            a2c[a][6]  = fmaf(hq.z, wv.y, a2c[a][6]);  a2c[a][7]  = fmaf(hq.w, wv.y, a2c[a][7]);
            a2c[a][8]  = fmaf(hq.x, wv.z, a2c[a][8]);  a2c[a][9]  = fmaf(hq.y, wv.z, a2c[a][9]);
            a2c[a][10] = fmaf(hq.z, wv.z, a2c[a][10]); a2c[a][11] = fmaf(hq.w, wv.z, a2c[a][11]);
            a2c[a][12] = fmaf(hq.x, wv.w, a2c[a][12]); a2c[a][13] = fmaf(hq.y, wv.w, a2c[a][13]);
            a2c[a][14] = fmaf(hq.z, wv.w, a2c[a][14]); a2c[a][15] = fmaf(hq.w, wv.w, a2c[a][15]);
        }
    }
    const float4 g2v  = *(const float4*)&g2[ch2];
    const float4 be2v = *(const float4*)&be2[ch2];
    float mx[AB][4];
    #pragma unroll
    for (int a = 0; a < AB; a++) {
        mx[a][0] = -INFINITY; mx[a][1] = -INFINITY; mx[a][2] = -INFINITY; mx[a][3] = -INFINITY;
        #pragma unroll
        for (int kk = 0; kk < 4; kk++) {
            float v0 = a2c[a][kk], v1 = a2c[a][4 + kk], v2 = a2c[a][8 + kk], v3 = a2c[a][12 + kk];
            float s  = (v0 + v1) + (v2 + v3);
            float s2 = (v0 * v0 + v1 * v1) + (v2 * v2 + v3 * v3);
            #pragma unroll
            for (int off = 16; off; off >>= 1) { s += __shfl_xor(s, off); s2 += __shfl_xor(s2, off); }
            float mu  = s  * (1.0f / H2);
            float var = s2 * (1.0f / H2) - mu * mu;
            float r = rsqrtf(var + 1e-6f);
            mx[a][0] = fmaxf(mx[a][0], fmaxf(fmaf((v0 - mu) * r, g2v.x, be2v.x), 0.0f));
            mx[a][1] = fmaxf(mx[a][1], fmaxf(fmaf((v1 - mu) * r, g2v.y, be2v.y), 0.0f));
            mx[a][2] = fmaxf(mx[a][2], fmaxf(fmaf((v2 - mu) * r, g2v.z, be2v.z), 0.0f));
            mx[a][3] = fmaxf(mx[a][3], fmaxf(fmaf((v3 - mu) * r, g2v.w, be2v.w), 0.0f));
        }
    }
    __syncthreads();                 // xst dead: alias as pmax[a][g][128]
    float* pmaxp = &xst[0][0];
    #pragma unroll
    for (int a = 0; a < AB; a++) {
        float4 q; q.x = mx[a][0]; q.y = mx[a][1]; q.z = mx[a][2]; q.w = mx[a][3];
        *(float4*)&pmaxp[(a * 8 + g) * H2 + ch2] = q;
    }
    __syncthreads();
    #pragma unroll
    for (int t = tid; t < AB * H2; t += 256) {
        const int a = t >> 7, ch = t & 127;
        float vv = pmaxp[(a * 8 + 0) * H2 + ch];
        #pragma unroll
        for (int gg = 1; gg < 8; gg++) vv = fmaxf(vv, pmaxp[(a * 8 + gg) * H2 + ch]);
        out[(size_t)(a0g + a) * H2 + ch] = vv;
    }
}

extern "C" void kernel_launch(void* const* d_in, const int* in_sizes, int n_in,
                              void* d_out, int out_size, void* d_ws, size_t ws_size,
                              hipStream_t stream) {
    const float* feat         = (const float*)d_in[0];
    const float* coord        = (const float*)d_in[1];
    const float* anchor_feat  = (const float*)d_in[2];
    const float* anchor_coord = (const float*)d_in[3];
    const float* W1  = (const float*)d_in[4];
    const float* b1  = (const float*)d_in[5];
    const float* g1  = (const float*)d_in[6];
    const float* be1 = (const float*)d_in[7];
    const float* W2  = (const float*)d_in[8];
    const float* b2  = (const float*)d_in[9];
    const float* g2  = (const float*)d_in[10];
    const float* be2 = (const float*)d_in[11];
    float* out = (float*)d_out;

    int*   maxn   = (int*)d_ws;                                  // 16 ints
    int*   idxbuf = (int*)d_ws + 16;                             // BB*MM*KNB ints
    float* c2buf  = (float*)((int*)d_ws + 16 + BB * MM * KNB);   // BB*NN floats

    init_kernel<<<1, 64, 0, stream>>>(maxn);
    c2_kernel<<<(BB * NN + 255) / 256, 256, 0, stream>>>(coord, c2buf);
    knn_kernel<<<BB * MM, 256, 0, stream>>>(coord, anchor_coord, c2buf, idxbuf, maxn);
    mlp_kernel<<<BB * MM / AB, 256, 0, stream>>>(feat, coord, anchor_feat, anchor_coord,
                                                 W1, b1, g1, be1, W2, b2, g2, be2,
                                                 maxn, idxbuf, out);
}